// Round 2
// baseline (2239.912 us; speedup 1.0000x reference)
//
#include <hip/hip_runtime.h>
#include <hip/hip_bf16.h>

#define T 256
#define H 400
#define G4 1600   // 4*H
#define WD 300
#define TD 100
#define MLP_H 400
#define NBLK_D 25       // blocks per direction (50 total)
#define HB 16           // h-rows per block
#define GR 64           // gate-rows per block (4*HB)
#define WSTR 202        // LDS weight row stride in u32 (bank-conflict pad)
#define NPAIR 200       // 400 h values -> 200 tagged 64-bit words
#define LSTM_GRID 194   // overlaunch: residues 0/1 mod 8 are active (25 each)

typedef _Float16 f16;
typedef _Float16 half2t __attribute__((ext_vector_type(2)));
typedef unsigned long long u64;
typedef unsigned int u32;

// ---------- math helpers ----------
__device__ __forceinline__ float fexp(float x) {
    return __builtin_amdgcn_exp2f(x * 1.4426950408889634f);
}
__device__ __forceinline__ float sigf(float x) {
    return __builtin_amdgcn_rcpf(1.0f + fexp(-x));
}
__device__ __forceinline__ float tanhf_fast(float x) {
    return 1.0f - 2.0f * __builtin_amdgcn_rcpf(1.0f + fexp(2.0f * x));
}
__device__ __forceinline__ unsigned short f16bits(f16 x) {
    union { f16 h; unsigned short u; } v; v.h = x; return v.u;
}
__device__ __forceinline__ u32 packh2(float a, float b) {
    half2t hv; hv.x = (_Float16)a; hv.y = (_Float16)b;
    return __builtin_bit_cast(u32, hv);
}

#if __has_builtin(__builtin_amdgcn_fdot2)
__device__ __forceinline__ float dot2u(u32 a, u32 b, float c) {
    return __builtin_amdgcn_fdot2(__builtin_bit_cast(half2t, a),
                                  __builtin_bit_cast(half2t, b), c, false);
}
#else
__device__ __forceinline__ float dot2u(u32 a, u32 b, float c) {
    half2t x = __builtin_bit_cast(half2t, a), y = __builtin_bit_cast(half2t, b);
    return fmaf((float)x.y, (float)y.y, fmaf((float)x.x, (float)y.x, c));
}
#endif

// system-scope (sc0 sc1) plain ops: bypass L1/L2, serviced at the IC --
// coherent across XCDs without RMWs or fences. SLOW path (R0-proven).
__device__ __forceinline__ u64 sysload(const u64* p) {
    return __hip_atomic_load(p, __ATOMIC_RELAXED, __HIP_MEMORY_SCOPE_SYSTEM);
}
__device__ __forceinline__ void sysstore(u64* p, u64 v) {
    __hip_atomic_store(p, v, __ATOMIC_RELAXED, __HIP_MEMORY_SCOPE_SYSTEM);
}
__device__ __forceinline__ u32 sysload32(const u32* p) {
    return __hip_atomic_load(p, __ATOMIC_RELAXED, __HIP_MEMORY_SCOPE_SYSTEM);
}
__device__ __forceinline__ void sysstore32(u32* p, u32 v) {
    __hip_atomic_store(p, v, __ATOMIC_RELAXED, __HIP_MEMORY_SCOPE_SYSTEM);
}

// sc0-only ops: bypass L1, serviced at the XCD's L2 (~200cy vs ~700cy IC).
// ONLY coherent when producer and consumer share an XCD. Used on a DEDICATED
// fast region; the slow region is never touched at this scope, so a stale
// fast line can never wedge the fallback. FAST path.
__device__ __forceinline__ u64 l2load(const u64* p) {
    u64 v;
    asm volatile("global_load_dwordx2 %0, %1, off sc0\n\t"
                 "s_waitcnt vmcnt(0)"
                 : "=v"(v) : "v"(p) : "memory");
    return v;
}
__device__ __forceinline__ void l2store(u64* p, u64 v) {
    asm volatile("global_store_dwordx2 %0, %1, off sc0"
                 :: "v"(p), "v"(v) : "memory");
}

// ---------- embedding gather ----------
__global__ void gather_k(const int* __restrict__ words, const int* __restrict__ tags,
                         const float* __restrict__ wemb, const float* __restrict__ temb,
                         float* __restrict__ x0) {
    int t = blockIdx.x;
    int w = words[t], g = tags[t];
    for (int c = threadIdx.x; c < H; c += 128) {
        float v = (c < WD) ? wemb[w * WD + c] : temb[g * TD + (c - WD)];
        x0[t * H + c] = v;
    }
}

// ---------- generic GEMM: out[t][r] = sum_k X[t*ldx+k]*W[r*ldw+wofs+k] + bias1[r]+bias2[r]
__global__ __launch_bounds__(256) void gemm_tn(
    const float* __restrict__ X, int ldx,
    const float* __restrict__ Wt, int ldw, int wofs,
    const float* __restrict__ bias1, const float* __restrict__ bias2,
    float* __restrict__ out, int ldo, int Rt, int K) {
    __shared__ float Xs[64][17];
    __shared__ float Ws[64][17];
    const int tid = threadIdx.x;
    const int t0 = blockIdx.x * 64, r0 = blockIdx.y * 64;
    const int lr = tid >> 2, kq = (tid & 3) * 4;
    const int ti = tid >> 4, rj = tid & 15;
    float acc[4][4] = {};
    for (int k0 = 0; k0 < K; k0 += 16) {
        float4 xv = *(const float4*)(X + (size_t)(t0 + lr) * ldx + k0 + kq);
        Xs[lr][kq + 0] = xv.x; Xs[lr][kq + 1] = xv.y;
        Xs[lr][kq + 2] = xv.z; Xs[lr][kq + 3] = xv.w;
        int r = r0 + lr;
        float4 wv = make_float4(0.f, 0.f, 0.f, 0.f);
        if (r < Rt) wv = *(const float4*)(Wt + (size_t)r * ldw + wofs + k0 + kq);
        Ws[lr][kq + 0] = wv.x; Ws[lr][kq + 1] = wv.y;
        Ws[lr][kq + 2] = wv.z; Ws[lr][kq + 3] = wv.w;
        __syncthreads();
#pragma unroll
        for (int k = 0; k < 16; k++) {
            float xr[4], wr[4];
#pragma unroll
            for (int m = 0; m < 4; m++) xr[m] = Xs[ti * 4 + m][k];
#pragma unroll
            for (int n = 0; n < 4; n++) wr[n] = Ws[rj * 4 + n][k];
#pragma unroll
            for (int m = 0; m < 4; m++)
#pragma unroll
                for (int n = 0; n < 4; n++)
                    acc[m][n] = fmaf(xr[m], wr[n], acc[m][n]);
        }
        __syncthreads();
    }
    int rq = r0 + rj * 4;
    if (rq < Rt) {
        float b[4];
#pragma unroll
        for (int n = 0; n < 4; n++) {
            int r = rq + n;
            b[n] = (bias1 ? bias1[r] : 0.f) + (bias2 ? bias2[r] : 0.f);
        }
#pragma unroll
        for (int m = 0; m < 4; m++) {
            int t = t0 + ti * 4 + m;
            float4 o;
            o.x = acc[m][0] + b[0]; o.y = acc[m][1] + b[1];
            o.z = acc[m][2] + b[2]; o.w = acc[m][3] + b[3];
            *(float4*)(out + (size_t)t * ldo + rq) = o;
        }
    }
}

// ---------- init: tagged words (slow + fast mirrors), zero claims ----------
__global__ void lstm_init5(const float* __restrict__ h0, u64* sA, u64* sB,
                           u64* fA, u64* fB, u32* __restrict__ claim) {
    int tid = threadIdx.x;
    const int TOT = 2 * 2 * NPAIR;
    for (int i = tid; i < TOT; i += 256) {
        sA[i] = 0xFFFFULL; sB[i] = 0xFFFFULL;
        fA[i] = 0xFFFFULL; fB[i] = 0xFFFFULL;
    }
    for (int i = tid; i < 128; i += 256) claim[i] = 0;   // both layers' claim regions
    __syncthreads();
    for (int p = tid; p < 2 * NPAIR; p += 256) {
        int d = p / NPAIR, pr = p - d * NPAIR;
        size_t off = (size_t)(d * 2 + 0) * NPAIR + pr;   // parity 0, tag 0
        f16 a0 = (f16)h0[d * H + 2 * pr], b0 = (f16)h0[d * H + 2 * pr + 1];
        u64 w0 = 0ULL | ((u64)f16bits(a0) << 16) | ((u64)f16bits(b0) << 32);
        sA[off] = w0; fA[off] = w0;
        f16 a1 = (f16)h0[2 * H + d * H + 2 * pr], b1 = (f16)h0[2 * H + d * H + 2 * pr + 1];
        u64 w1 = 0ULL | ((u64)f16bits(a1) << 16) | ((u64)f16bits(b1) << 32);
        sB[off] = w1; fB[off] = w1;
    }
}

// ---------- persistent LSTM layer v10: LDS weights + LDS-resident G +
// same-XCD L2 broadcast with hang-proof dual-store protocol.
// Overlaunched grid (194): blockIdx%8 in {0,1} = direction, blockIdx/8 =
// block; other residues exit (CP round-robins workgroups over the 8 XCDs,
// so one residue class = one XCD). Blocks publish XCC_ID; if a direction's
// 25 blocks share an XCD, pollers use the FAST region at L2 scope (~200cy);
// producers ALWAYS publish to the slow IC region and additionally mirror to
// the fast region when the check passed. Pollers bound the fast spin (4096)
// and fall back sticky to the slow region -- since fast/slow are disjoint
// lines and slow is only ever IC-scope, no stale-L2 wedge is possible.
// All G (256 steps x 64 rows) preloaded to LDS: no global load on the
// per-step critical path. LDS total ~118.3 KB (1 block/CU).
__global__ __launch_bounds__(512, 1) void lstm_layer8(
    const float* __restrict__ G,     // [2][T][G4] gate inputs, biases folded
    const float* __restrict__ Whh,   // [2][G4][H]
    const float* __restrict__ c0l,   // [2][H] this layer
    float* __restrict__ xout,        // [T][2H]
    u64* __restrict__ slots,         // [2][2][NPAIR] slow (IC scope)
    u64* __restrict__ fslots,        // [2][2][NPAIR] fast (L2 scope)
    u32* __restrict__ claim) {       // [50] xcd+1 per role, pre-zeroed
    const int m8 = blockIdx.x & 7, q8 = blockIdx.x >> 3;
    if (m8 >= 2 || q8 >= NBLK_D) return;
    const int dir = m8, blk = q8;
    const int role = dir * NBLK_D + blk;
    const int tid = threadIdx.x;
    const float* Wd = Whh + (size_t)dir * G4 * H;
    const float* Gd = G + (size_t)dir * T * G4;
    u64* sd  = slots  + (size_t)dir * 2 * NPAIR;
    u64* fsd = fslots + (size_t)dir * 2 * NPAIR;

    __shared__ u32 wlds[GR * WSTR];            // 64 rows x 202 u32 = 50.5 KiB
    __shared__ __align__(16) u32 hsh[NPAIR];   // h_s as 200 packed half2
    __shared__ float gsum[GR];                 // per-gate-row matvec sums
    __shared__ __align__(16) float gall[T * GR]; // all G for this block, 64 KiB
    __shared__ int s_fast;
    __shared__ int s_slow;                     // sticky fast-path abandon flag

    // publish our XCD early (overlaps the LDS fills below)
    if (tid == 0) {
        u32 x;
        asm volatile("s_getreg_b32 %0, hwreg(HW_REG_XCC_ID, 0, 4)" : "=s"(x));
        sysstore32(&claim[role], x + 1);
        s_slow = 0;
    }

    // ---- one-time: pack weights fp32 -> half2 into LDS ----
    for (int idx = tid; idx < GR * 100; idx += 512) {
        int row = idx / 100, c4 = idx - row * 100;
        int g = row >> 4, r = row & 15;
        const float4* src = (const float4*)(Wd + (size_t)(g * H + blk * HB + r) * H);
        float4 f = src[c4];
        *(uint2*)&wlds[row * WSTR + c4 * 2] =
            make_uint2(packh2(f.x, f.y), packh2(f.z, f.w));
    }
    // ---- one-time: preload ALL step inputs G into LDS ----
    for (int idx = tid; idx < T * GR / 4; idx += 512) {   // 4096 float4
        int t = idx >> 4, rest = idx & 15, g = rest >> 2, q = rest & 3;
        float4 v = *(const float4*)(Gd + (size_t)t * G4 + g * H + blk * HB + q * 4);
        *(float4*)&gall[t * GR + g * HB + q * 4] = v;
    }
    // own h0 words into LDS (slow region, IC scope -- read-only here)
    if (tid < 8) {
        u64 v = sysload(sd + blk * 8 + tid);       // parity 0, tag 0
        hsh[blk * 8 + tid] = (u32)(v >> 16);
    }
    // ---- claim verification: same-XCD fast path? (bounded) ----
    if (tid == 0) {
        u32 ref = 0; int ok = 1;
        for (int i = 0; i < NBLK_D; i++) {
            u32 v = 0; int sp = 0;
            do { v = sysload32(&claim[dir * NBLK_D + i]); } while (v == 0 && ++sp < (1 << 20));
            if (v == 0) { ok = 0; break; }
            if (i == 0) ref = v; else ok &= (v == ref);
        }
        s_fast = ok;
    }
    float c = (tid < 64) ? c0l[dir * H + blk * HB + (tid & 15)] : 0.f;
    __syncthreads();
    const int fastp = s_fast;

#pragma clang loop unroll(disable)
    for (int s = 0; s < T; ++s) {
        if (tid >= 256 && tid < 448) {
            // poller: one foreign word (parity s&1, tag s)
            int f = tid - 256;
            int widx = f + (f >= blk * 8 ? 8 : 0);
            u64 v = 0;
            int got = 0;
            if (fastp && !s_slow) {
                u64* fsrc = fsd + (size_t)(s & 1) * NPAIR + widx;
                v = l2load(fsrc);
                int spins = 0;
                while ((unsigned)(v & 0xFFFFULL) != (unsigned)s && spins < 4096) {
                    v = l2load(fsrc); ++spins;
                }
                if ((unsigned)(v & 0xFFFFULL) == (unsigned)s) got = 1;
                else s_slow = 1;   // sticky: abandon fast path for this block
            }
            if (!got) {
                u64* src = sd + (size_t)(s & 1) * NPAIR + widx;
                v = sysload(src);
                int spins = 0;
                while ((unsigned)(v & 0xFFFFULL) != (unsigned)s) {
                    if (++spins > 16384) {
                        v = __hip_atomic_fetch_add(src, 0ULL, __ATOMIC_RELAXED,
                                                   __HIP_MEMORY_SCOPE_AGENT);
                    } else {
                        v = sysload(src);
                    }
                }
            }
            hsh[widx] = (u32)(v >> 16);
        }
        __syncthreads();   // (A) h_s complete in LDS

        if (tid < 256) {
            const int row = tid >> 2, sl = tid & 3;
            const u32* wp = &wlds[row * WSTR + sl * 50];
            const u32* hp = &hsh[sl * 50];
            float a0 = 0.f, a1 = 0.f, a2 = 0.f, a3 = 0.f;
#pragma unroll
            for (int i = 0; i < 12; ++i) {
                uint2 wv0 = *(const uint2*)&wp[4 * i];
                uint2 hv0 = *(const uint2*)&hp[4 * i];
                uint2 wv1 = *(const uint2*)&wp[4 * i + 2];
                uint2 hv1 = *(const uint2*)&hp[4 * i + 2];
                a0 = dot2u(wv0.x, hv0.x, a0);
                a1 = dot2u(wv0.y, hv0.y, a1);
                a2 = dot2u(wv1.x, hv1.x, a2);
                a3 = dot2u(wv1.y, hv1.y, a3);
            }
            {
                uint2 wv = *(const uint2*)&wp[48];
                uint2 hv = *(const uint2*)&hp[48];
                a0 = dot2u(wv.x, hv.x, a0);
                a1 = dot2u(wv.y, hv.y, a1);
            }
            float a = (a0 + a1) + (a2 + a3);
            a += __shfl_xor(a, 1);    // combine the 4 k-slices (adjacent lanes)
            a += __shfl_xor(a, 2);
            if (sl == 0) gsum[row] = a;
        }
        __syncthreads();   // (B) sums ready

        if (tid < 64) {    // wave 0: gate math + publish, intra-wave only
            const int r = tid & 15;
            const int tt = dir ? (T - 1 - s) : s;
            const float* gc = &gall[tt * GR];
            float iv = gsum[r]      + gc[r];
            float fv = gsum[16 + r] + gc[16 + r];
            float gv = gsum[32 + r] + gc[32 + r];
            float ov = gsum[48 + r] + gc[48 + r];
            float cn = sigf(fv) * c + sigf(iv) * tanhf_fast(gv);
            c = cn;
            float hn = sigf(ov) * tanhf_fast(cn);
            u32 hb = (u32)f16bits((f16)hn);
            u32 lo = __shfl(hb, (2 * tid) & 63);
            u32 hi = __shfl(hb, (2 * tid + 1) & 63);
            if (tid < 8) {
                u32 pk = (lo & 0xFFFFu) | (hi << 16);
                hsh[blk * 8 + tid] = pk;   // own slice of h_{s+1}, LDS fast-path
                u64 w = (u64)(unsigned)(s + 1) | ((u64)pk << 16);
                size_t so = (size_t)((s + 1) & 1) * NPAIR + blk * 8 + tid;
                if (fastp) l2store(fsd + so, w);   // fast mirror (L2, same XCD)
                sysstore(sd + so, w);              // always: slow region (IC)
            }
            if (tid < 16)
                xout[(size_t)tt * (2 * H) + dir * H + blk * HB + tid] = hn;
        }
    }
}

// ---------- fused pairwise scorer ----------
__global__ __launch_bounds__(256) void scores_k(
    const float* __restrict__ pi, const float* __restrict__ pj,
    const float* __restrict__ w2, const float* __restrict__ b2p,
    float* __restrict__ out) {
    __shared__ float Ps[16][401];
    __shared__ float Qs[16][401];
    __shared__ float w2s[400];
    const int tid = threadIdx.x;
    const int i0 = blockIdx.y * 16, j0 = blockIdx.x * 16;
    for (int r = 0; r < 16; r++) {
        for (int k = tid; k < MLP_H; k += 256) {
            Ps[r][k] = pi[(size_t)(i0 + r) * MLP_H + k];
            Qs[r][k] = pj[(size_t)(j0 + r) * MLP_H + k];
        }
    }
    for (int k = tid; k < MLP_H; k += 256) w2s[k] = w2[k];
    __syncthreads();
    const int ti = tid >> 4, tj = tid & 15;
    float acc = 0.f;
#pragma unroll 4
    for (int k = 0; k < MLP_H; k++) {
        float x = Ps[ti][k] + Qs[tj][k];
        acc = fmaf(w2s[k], tanhf_fast(x), acc);
    }
    const int i = i0 + ti, j = j0 + tj;
    out[(size_t)i * T + j] = (i == j) ? 0.f : (acc + b2p[0]);
}

extern "C" void kernel_launch(void* const* d_in, const int* in_sizes, int n_in,
                              void* d_out, int out_size, void* d_ws, size_t ws_size,
                              hipStream_t stream) {
    const int*   words = (const int*)d_in[0];
    const int*   tags  = (const int*)d_in[1];
    const float* wemb  = (const float*)d_in[2];
    const float* temb  = (const float*)d_in[3];
    const float* Wih0  = (const float*)d_in[4];
    const float* Whh0  = (const float*)d_in[5];
    const float* bih0  = (const float*)d_in[6];
    const float* bhh0  = (const float*)d_in[7];
    const float* Wih1  = (const float*)d_in[8];
    const float* Whh1  = (const float*)d_in[9];
    const float* bih1  = (const float*)d_in[10];
    const float* bhh1  = (const float*)d_in[11];
    const float* W1    = (const float*)d_in[12];
    const float* b1    = (const float*)d_in[13];
    const float* W2    = (const float*)d_in[14];
    const float* b2    = (const float*)d_in[15];
    const float* h0    = (const float*)d_in[16];
    const float* c0    = (const float*)d_in[17];
    float* out = (float*)d_out;

    float* W = (float*)d_ws;
    float* x0   = W;                 // 256*400 (dead after layer-0 GEMMs)
    float* x1   = W + 102400;        // 256*800
    float* hvec = W + 307200;        // 256*800
    float* Gb   = W + 512000;        // 2*256*1600 (reused for both layers)
    float* pi   = W + 1331200;       // 256*400
    float* pj   = W + 1433600;       // 256*400
    // word arrays overlap x0's region (x0 dead before lstm_init5 runs)
    u64* slotsA  = (u64*)W;                              // 800 u64 (slow, IC)
    u64* slotsB  = (u64*)(W + 2048);                     // 800 u64 (slow, IC)
    u32* claimA  = (u32*)(W + 4096);                     // 64 u32 (layer 0)
    u32* claimB  = claimA + 64;                          // 64 u32 (layer 1)
    u64* fslotsA = (u64*)(W + 8192);                     // 800 u64 (fast, L2)
    u64* fslotsB = (u64*)(W + 12288);                    // 800 u64 (fast, L2)

    // 1. embedding gather
    gather_k<<<T, 128, 0, stream>>>(words, tags, wemb, temb, x0);

    // 2. layer-0 gate inputs
    for (int d = 0; d < 2; d++) {
        gemm_tn<<<dim3(4, 25), 256, 0, stream>>>(
            x0, H, Wih0 + (size_t)d * G4 * H, H, 0,
            bih0 + d * G4, bhh0 + d * G4,
            Gb + (size_t)d * T * G4, G4, G4, H);
    }
    // 3. init tagged words + claim regions (x0 now dead), then LSTM layer 0
    lstm_init5<<<1, 256, 0, stream>>>(h0, slotsA, slotsB, fslotsA, fslotsB, claimA);
    lstm_layer8<<<LSTM_GRID, 512, 0, stream>>>(Gb, Whh0, c0, x1, slotsA, fslotsA, claimA);

    // 4. layer-1 gate inputs (K=800)
    for (int d = 0; d < 2; d++) {
        gemm_tn<<<dim3(4, 25), 256, 0, stream>>>(
            x1, 2 * H, Wih1 + (size_t)d * G4 * (2 * H), 2 * H, 0,
            bih1 + d * G4, bhh1 + d * G4,
            Gb + (size_t)d * T * G4, G4, G4, 2 * H);
    }
    // 5. LSTM layer 1
    lstm_layer8<<<LSTM_GRID, 512, 0, stream>>>(Gb, Whh1, c0 + 2 * H, hvec, slotsB, fslotsB, claimB);

    // 6. pi = hvec @ W1a.T + b1 ; pj = hvec @ W1b.T
    gemm_tn<<<dim3(4, 7), 256, 0, stream>>>(
        hvec, 2 * H, W1, G4, 0, b1, nullptr, pi, MLP_H, MLP_H, 2 * H);
    gemm_tn<<<dim3(4, 7), 256, 0, stream>>>(
        hvec, 2 * H, W1, G4, 2 * H, nullptr, nullptr, pj, MLP_H, MLP_H, 2 * H);

    // 7. fused pairwise scores
    scores_k<<<dim3(16, 16), 256, 0, stream>>>(pi, pj, W2, b2, out);
}

// Round 3
// 1959.472 us; speedup vs baseline: 1.1431x; 1.1431x over previous
//
#include <hip/hip_runtime.h>
#include <hip/hip_bf16.h>

#define T 256
#define H 400
#define G4 1600   // 4*H
#define WD 300
#define TD 100
#define MLP_H 400
#define NBLK_D 25       // blocks per direction (50 total)
#define HB 16           // h-rows per block
#define GR 64           // gate-rows per block (4*HB)
#define WSTR 202        // LDS weight row stride in u32 (bank-conflict pad)
#define NPAIR 200       // 400 h values -> 200 tagged 64-bit words

typedef _Float16 f16;
typedef _Float16 half2t __attribute__((ext_vector_type(2)));
typedef unsigned long long u64;
typedef unsigned int u32;

// ---------- math helpers ----------
__device__ __forceinline__ float fexp(float x) {
    return __builtin_amdgcn_exp2f(x * 1.4426950408889634f);
}
__device__ __forceinline__ float sigf(float x) {
    return __builtin_amdgcn_rcpf(1.0f + fexp(-x));
}
__device__ __forceinline__ float tanhf_fast(float x) {
    return 1.0f - 2.0f * __builtin_amdgcn_rcpf(1.0f + fexp(2.0f * x));
}
__device__ __forceinline__ unsigned short f16bits(f16 x) {
    union { f16 h; unsigned short u; } v; v.h = x; return v.u;
}
__device__ __forceinline__ u32 packh2(float a, float b) {
    half2t hv; hv.x = (_Float16)a; hv.y = (_Float16)b;
    return __builtin_bit_cast(u32, hv);
}

#if __has_builtin(__builtin_amdgcn_fdot2)
__device__ __forceinline__ float dot2u(u32 a, u32 b, float c) {
    return __builtin_amdgcn_fdot2(__builtin_bit_cast(half2t, a),
                                  __builtin_bit_cast(half2t, b), c, false);
}
#else
__device__ __forceinline__ float dot2u(u32 a, u32 b, float c) {
    half2t x = __builtin_bit_cast(half2t, a), y = __builtin_bit_cast(half2t, b);
    return fmaf((float)x.y, (float)y.y, fmaf((float)x.x, (float)y.x, c));
}
#endif

// system-scope (sc0 sc1) plain ops: bypass L1/L2, serviced at the IC --
// coherent across XCDs without RMWs or fences. (R0-proven transport.)
__device__ __forceinline__ u64 sysload(const u64* p) {
    return __hip_atomic_load(p, __ATOMIC_RELAXED, __HIP_MEMORY_SCOPE_SYSTEM);
}
__device__ __forceinline__ void sysstore(u64* p, u64 v) {
    __hip_atomic_store(p, v, __ATOMIC_RELAXED, __HIP_MEMORY_SCOPE_SYSTEM);
}

// ---------- embedding gather ----------
__global__ void gather_k(const int* __restrict__ words, const int* __restrict__ tags,
                         const float* __restrict__ wemb, const float* __restrict__ temb,
                         float* __restrict__ x0) {
    int t = blockIdx.x;
    int w = words[t], g = tags[t];
    for (int c = threadIdx.x; c < H; c += 128) {
        float v = (c < WD) ? wemb[w * WD + c] : temb[g * TD + (c - WD)];
        x0[t * H + c] = v;
    }
}

// ---------- generic GEMM: out[t][r] = sum_k X[t*ldx+k]*W[r*ldw+wofs+k] + bias1[r]+bias2[r]
__global__ __launch_bounds__(256) void gemm_tn(
    const float* __restrict__ X, int ldx,
    const float* __restrict__ Wt, int ldw, int wofs,
    const float* __restrict__ bias1, const float* __restrict__ bias2,
    float* __restrict__ out, int ldo, int Rt, int K) {
    __shared__ float Xs[64][17];
    __shared__ float Ws[64][17];
    const int tid = threadIdx.x;
    const int t0 = blockIdx.x * 64, r0 = blockIdx.y * 64;
    const int lr = tid >> 2, kq = (tid & 3) * 4;
    const int ti = tid >> 4, rj = tid & 15;
    float acc[4][4] = {};
    for (int k0 = 0; k0 < K; k0 += 16) {
        float4 xv = *(const float4*)(X + (size_t)(t0 + lr) * ldx + k0 + kq);
        Xs[lr][kq + 0] = xv.x; Xs[lr][kq + 1] = xv.y;
        Xs[lr][kq + 2] = xv.z; Xs[lr][kq + 3] = xv.w;
        int r = r0 + lr;
        float4 wv = make_float4(0.f, 0.f, 0.f, 0.f);
        if (r < Rt) wv = *(const float4*)(Wt + (size_t)r * ldw + wofs + k0 + kq);
        Ws[lr][kq + 0] = wv.x; Ws[lr][kq + 1] = wv.y;
        Ws[lr][kq + 2] = wv.z; Ws[lr][kq + 3] = wv.w;
        __syncthreads();
#pragma unroll
        for (int k = 0; k < 16; k++) {
            float xr[4], wr[4];
#pragma unroll
            for (int m = 0; m < 4; m++) xr[m] = Xs[ti * 4 + m][k];
#pragma unroll
            for (int n = 0; n < 4; n++) wr[n] = Ws[rj * 4 + n][k];
#pragma unroll
            for (int m = 0; m < 4; m++)
#pragma unroll
                for (int n = 0; n < 4; n++)
                    acc[m][n] = fmaf(xr[m], wr[n], acc[m][n]);
        }
        __syncthreads();
    }
    int rq = r0 + rj * 4;
    if (rq < Rt) {
        float b[4];
#pragma unroll
        for (int n = 0; n < 4; n++) {
            int r = rq + n;
            b[n] = (bias1 ? bias1[r] : 0.f) + (bias2 ? bias2[r] : 0.f);
        }
#pragma unroll
        for (int m = 0; m < 4; m++) {
            int t = t0 + ti * 4 + m;
            float4 o;
            o.x = acc[m][0] + b[0]; o.y = acc[m][1] + b[1];
            o.z = acc[m][2] + b[2]; o.w = acc[m][3] + b[3];
            *(float4*)(out + (size_t)t * ldo + rq) = o;
        }
    }
}

// ---------- init: tagged words, contiguous [dir][parity][NPAIR] ----------
__global__ void lstm_init5(const float* __restrict__ h0, u64* sA, u64* sB) {
    int tid = threadIdx.x;
    const int TOT = 2 * 2 * NPAIR;
    for (int i = tid; i < TOT; i += 256) { sA[i] = 0xFFFFULL; sB[i] = 0xFFFFULL; }
    __syncthreads();
    for (int p = tid; p < 2 * NPAIR; p += 256) {
        int d = p / NPAIR, pr = p - d * NPAIR;
        size_t off = (size_t)(d * 2 + 0) * NPAIR + pr;   // parity 0, tag 0
        f16 a0 = (f16)h0[d * H + 2 * pr], b0 = (f16)h0[d * H + 2 * pr + 1];
        sA[off] = 0ULL | ((u64)f16bits(a0) << 16) | ((u64)f16bits(b0) << 32);
        f16 a1 = (f16)h0[2 * H + d * H + 2 * pr], b1 = (f16)h0[2 * H + d * H + 2 * pr + 1];
        sB[off] = 0ULL | ((u64)f16bits(a1) << 16) | ((u64)f16bits(b1) << 32);
    }
}

// ---------- persistent LSTM layer v11: single-barrier step schedule ----------
// grid = 50 (dir = b/25, blk = b%25), 512 threads. Transport = R0's proven
// IC-scope tagged-word protocol (unchanged). New intra-block schedule:
//  - lane mapping puts all 4 gate sums of an h-row in ONE wave: lane l =
//    (gate g=l>>4, row j=(l>>2)&3, slice sl=l&3); wave w owns h-rows 4w..4w+3.
//    After the 2-shfl slice combine, 4 __shfl gather the gate sums -> gate
//    math runs in ALL 4 worker waves (was wave-0-only), c lives in-lane.
//  - hsh2 is parity-double-buffered: workers write h_{s+1} words while h_s
//    is still being read -> barrier B and the gsum LDS round-trip are GONE.
//    One __syncthreads per step.
//  - pollers poll pre-barrier, i.e. they poll step s+1's words DURING the
//    workers' step-s compute -> IC publish->detect latency hides under
//    compute. Skew safety (<=1 step) inherited from the R0 protocol: a
//    block publishes tag s+1 only after reading all tag-s words, which
//    implies every block has read the tag s-1 words its store overwrites.
__global__ __launch_bounds__(512, 1) void lstm_layer8(
    const float* __restrict__ G,     // [2][T][G4] gate inputs, biases folded
    const float* __restrict__ Whh,   // [2][G4][H]
    const float* __restrict__ c0l,   // [2][H] this layer
    float* __restrict__ xout,        // [T][2H]
    u64* __restrict__ slots) {       // [2][2][NPAIR]
    const int role = blockIdx.x;
    const int dir = role / NBLK_D, blk = role - dir * NBLK_D;
    const int tid = threadIdx.x;
    const float* Wd = Whh + (size_t)dir * G4 * H;
    const float* Gd = G + (size_t)dir * T * G4;
    u64* sd = slots + (size_t)dir * 2 * NPAIR;

    __shared__ u32 wlds[GR * WSTR];              // 64 rows x 202 u32 = 50.5 KiB
    __shared__ __align__(16) u32 hsh2[2][NPAIR]; // h double-buffer (parity)
    __shared__ float gsh[2][GR];                 // staged G, double-buffered

    // ---- one-time: pack weights fp32 -> half2 into LDS ----
    for (int idx = tid; idx < GR * 100; idx += 512) {
        int row = idx / 100, c4 = idx - row * 100;
        int g = row >> 4, r = row & 15;
        const float4* src = (const float4*)(Wd + (size_t)(g * H + blk * HB + r) * H);
        float4 f = src[c4];
        *(uint2*)&wlds[row * WSTR + c4 * 2] =
            make_uint2(packh2(f.x, f.y), packh2(f.z, f.w));
    }
    // pre-stage G(0); own h0 words into hsh2[0]
    if (tid >= 448) {
        int i = tid - 448, gg = i >> 4, rr = i & 15;
        int tt0 = dir ? (T - 1) : 0;
        gsh[0][i] = Gd[(size_t)tt0 * G4 + gg * H + blk * HB + rr];
    } else if (tid < 8) {
        u64 v = sysload(sd + blk * 8 + tid);       // parity 0, tag 0
        hsh2[0][blk * 8 + tid] = (u32)(v >> 16);
    }
    // worker-lane constants (tid < 256): wave wv, gate g, row j, slice sl
    const int l  = tid & 63;
    const int wv = tid >> 6;          // 0..3 for workers
    const int sl = l & 3;
    const int gg = l >> 4;            // gate 0..3
    const int jj = (l >> 2) & 3;      // h-row within wave quad
    float c = 0.f;
    if (tid < 256) c = c0l[dir * H + blk * HB + wv * 4 + jj];
    __syncthreads();

#pragma clang loop unroll(disable)
    for (int s = 0; s < T; ++s) {
        if (tid >= 256 && tid < 448) {
            // poller (pre-barrier): one foreign word (parity s&1, tag s).
            // Runs one step AHEAD of own workers -> overlaps their compute.
            int f = tid - 256;
            int widx = f + (f >= blk * 8 ? 8 : 0);
            u64* src = sd + (size_t)(s & 1) * NPAIR + widx;
            u64 v = sysload(src);
            int spins = 0;
            while ((unsigned)(v & 0xFFFFULL) != (unsigned)s) {
                if (++spins > 16384) {
                    v = __hip_atomic_fetch_add(src, 0ULL, __ATOMIC_RELAXED,
                                               __HIP_MEMORY_SCOPE_AGENT);
                } else {
                    v = sysload(src);
                }
            }
            hsh2[s & 1][widx] = (u32)(v >> 16);
        }
        __syncthreads();   // (A) h_s complete in hsh2[s&1]; gsh[s&1] ready

        if (tid >= 448) {
            // stager (post-barrier): G(s+1) -> gsh[(s+1)&1]. Safe: next write
            // to gsh[s&1] happens only after barrier A(s+1), i.e. after all
            // workers finished reading it.
            int sn = (s + 1 < T) ? (s + 1) : s;
            int tt = dir ? (T - 1 - sn) : sn;
            int i = tid - 448;
            gsh[(s + 1) & 1][i] = Gd[(size_t)tt * G4 + (i >> 4) * H + blk * HB + (i & 15)];
        } else if (tid < 256) {
            // worker: matvec for gate row R = gg*16 + wv*4 + jj
            const int R = gg * 16 + wv * 4 + jj;
            const u32* wp = &wlds[R * WSTR + sl * 50];
            const u32* hp = &hsh2[s & 1][sl * 50];
            float a0 = 0.f, a1 = 0.f, a2 = 0.f, a3 = 0.f;
#pragma unroll
            for (int i = 0; i < 12; ++i) {
                uint2 wv0 = *(const uint2*)&wp[4 * i];
                uint2 hv0 = *(const uint2*)&hp[4 * i];
                uint2 wv1 = *(const uint2*)&wp[4 * i + 2];
                uint2 hv1 = *(const uint2*)&hp[4 * i + 2];
                a0 = dot2u(wv0.x, hv0.x, a0);
                a1 = dot2u(wv0.y, hv0.y, a1);
                a2 = dot2u(wv1.x, hv1.x, a2);
                a3 = dot2u(wv1.y, hv1.y, a3);
            }
            {
                uint2 wvx = *(const uint2*)&wp[48];
                uint2 hvx = *(const uint2*)&hp[48];
                a0 = dot2u(wvx.x, hvx.x, a0);
                a1 = dot2u(wvx.y, hvx.y, a1);
            }
            float a = (a0 + a1) + (a2 + a3);
            a += __shfl_xor(a, 1);    // combine 4 k-slices
            a += __shfl_xor(a, 2);
            // gather the 4 gate sums for my h-row jj (each lives in lane 16*g'+4*jj)
            float iv = __shfl(a, 4 * jj);
            float fv = __shfl(a, 4 * jj + 16);
            float gv = __shfl(a, 4 * jj + 32);
            float ov = __shfl(a, 4 * jj + 48);
            const int ro = wv * 4 + jj;
            const float* gc = gsh[s & 1];
            iv += gc[ro]; fv += gc[16 + ro]; gv += gc[32 + ro]; ov += gc[48 + ro];
            float cn = sigf(fv) * c + sigf(iv) * tanhf_fast(gv);
            c = cn;
            float hn = sigf(ov) * tanhf_fast(cn);
            u32 hb = (u32)f16bits((f16)hn);
            u32 h0b = __shfl(hb, 0), h1b = __shfl(hb, 4);
            u32 h2b = __shfl(hb, 8), h3b = __shfl(hb, 12);
            const int tt = dir ? (T - 1 - s) : s;
            if (sl == 0 && gg == 0)   // lanes 0,4,8,12: one store per h-row
                xout[(size_t)tt * (2 * H) + dir * H + blk * HB + wv * 4 + jj] = hn;
            if (l == 0) {
                u32 pk0 = (h0b & 0xFFFFu) | (h1b << 16);
                hsh2[(s + 1) & 1][blk * 8 + 2 * wv] = pk0;   // own word, next parity
                sysstore(sd + (size_t)((s + 1) & 1) * NPAIR + blk * 8 + 2 * wv,
                         (u64)(unsigned)(s + 1) | ((u64)pk0 << 16));
            } else if (l == 1) {
                u32 pk1 = (h2b & 0xFFFFu) | (h3b << 16);
                hsh2[(s + 1) & 1][blk * 8 + 2 * wv + 1] = pk1;
                sysstore(sd + (size_t)((s + 1) & 1) * NPAIR + blk * 8 + 2 * wv + 1,
                         (u64)(unsigned)(s + 1) | ((u64)pk1 << 16));
            }
        }
    }
}

// ---------- fused pairwise scorer ----------
__global__ __launch_bounds__(256) void scores_k(
    const float* __restrict__ pi, const float* __restrict__ pj,
    const float* __restrict__ w2, const float* __restrict__ b2p,
    float* __restrict__ out) {
    __shared__ float Ps[16][401];
    __shared__ float Qs[16][401];
    __shared__ float w2s[400];
    const int tid = threadIdx.x;
    const int i0 = blockIdx.y * 16, j0 = blockIdx.x * 16;
    for (int r = 0; r < 16; r++) {
        for (int k = tid; k < MLP_H; k += 256) {
            Ps[r][k] = pi[(size_t)(i0 + r) * MLP_H + k];
            Qs[r][k] = pj[(size_t)(j0 + r) * MLP_H + k];
        }
    }
    for (int k = tid; k < MLP_H; k += 256) w2s[k] = w2[k];
    __syncthreads();
    const int ti = tid >> 4, tj = tid & 15;
    float acc = 0.f;
#pragma unroll 4
    for (int k = 0; k < MLP_H; k++) {
        float x = Ps[ti][k] + Qs[tj][k];
        acc = fmaf(w2s[k], tanhf_fast(x), acc);
    }
    const int i = i0 + ti, j = j0 + tj;
    out[(size_t)i * T + j] = (i == j) ? 0.f : (acc + b2p[0]);
}

extern "C" void kernel_launch(void* const* d_in, const int* in_sizes, int n_in,
                              void* d_out, int out_size, void* d_ws, size_t ws_size,
                              hipStream_t stream) {
    const int*   words = (const int*)d_in[0];
    const int*   tags  = (const int*)d_in[1];
    const float* wemb  = (const float*)d_in[2];
    const float* temb  = (const float*)d_in[3];
    const float* Wih0  = (const float*)d_in[4];
    const float* Whh0  = (const float*)d_in[5];
    const float* bih0  = (const float*)d_in[6];
    const float* bhh0  = (const float*)d_in[7];
    const float* Wih1  = (const float*)d_in[8];
    const float* Whh1  = (const float*)d_in[9];
    const float* bih1  = (const float*)d_in[10];
    const float* bhh1  = (const float*)d_in[11];
    const float* W1    = (const float*)d_in[12];
    const float* b1    = (const float*)d_in[13];
    const float* W2    = (const float*)d_in[14];
    const float* b2    = (const float*)d_in[15];
    const float* h0    = (const float*)d_in[16];
    const float* c0    = (const float*)d_in[17];
    float* out = (float*)d_out;

    float* W = (float*)d_ws;
    float* x0   = W;                 // 256*400 (dead after layer-0 GEMMs)
    float* x1   = W + 102400;        // 256*800
    float* hvec = W + 307200;        // 256*800
    float* Gb   = W + 512000;        // 2*256*1600 (reused for both layers)
    float* pi   = W + 1331200;       // 256*400
    float* pj   = W + 1433600;       // 256*400
    // word arrays overlap x0's region (x0 dead before lstm_init5 runs)
    u64* slotsA = (u64*)W;                               // 800 u64
    u64* slotsB = (u64*)(W + 2048);                      // 800 u64

    // 1. embedding gather
    gather_k<<<T, 128, 0, stream>>>(words, tags, wemb, temb, x0);

    // 2. layer-0 gate inputs
    for (int d = 0; d < 2; d++) {
        gemm_tn<<<dim3(4, 25), 256, 0, stream>>>(
            x0, H, Wih0 + (size_t)d * G4 * H, H, 0,
            bih0 + d * G4, bhh0 + d * G4,
            Gb + (size_t)d * T * G4, G4, G4, H);
    }
    // 3. init tagged words (x0 now dead), then LSTM layer 0
    lstm_init5<<<1, 256, 0, stream>>>(h0, slotsA, slotsB);
    lstm_layer8<<<2 * NBLK_D, 512, 0, stream>>>(Gb, Whh0, c0, x1, slotsA);

    // 4. layer-1 gate inputs (K=800)
    for (int d = 0; d < 2; d++) {
        gemm_tn<<<dim3(4, 25), 256, 0, stream>>>(
            x1, 2 * H, Wih1 + (size_t)d * G4 * (2 * H), 2 * H, 0,
            bih1 + d * G4, bhh1 + d * G4,
            Gb + (size_t)d * T * G4, G4, G4, 2 * H);
    }
    // 5. LSTM layer 1
    lstm_layer8<<<2 * NBLK_D, 512, 0, stream>>>(Gb, Whh1, c0 + 2 * H, hvec, slotsB);

    // 6. pi = hvec @ W1a.T + b1 ; pj = hvec @ W1b.T
    gemm_tn<<<dim3(4, 7), 256, 0, stream>>>(
        hvec, 2 * H, W1, G4, 0, b1, nullptr, pi, MLP_H, MLP_H, 2 * H);
    gemm_tn<<<dim3(4, 7), 256, 0, stream>>>(
        hvec, 2 * H, W1, G4, 2 * H, nullptr, nullptr, pj, MLP_H, MLP_H, 2 * H);

    // 7. fused pairwise scores
    scores_k<<<dim3(16, 16), 256, 0, stream>>>(pi, pj, W2, b2, out);
}

// Round 4
// 1793.231 us; speedup vs baseline: 1.2491x; 1.0927x over previous
//
#include <hip/hip_runtime.h>
#include <hip/hip_bf16.h>

#define T 256
#define H 400
#define G4 1600   // 4*H
#define WD 300
#define TD 100
#define MLP_H 400
#define NBLK_D 10       // blocks per direction (20 total)
#define HB 40           // h-rows per block
#define GR 160          // gate-rows per block (4*HB)
#define WSTR 202        // LDS weight row stride in u32 (bank-conflict pad)
#define NPAIR 200       // 400 h values -> 200 tagged 64-bit words
#define OWNW 20         // own words per block (HB/2)
#define FORW 180        // foreign words per block

typedef _Float16 f16;
typedef _Float16 half2t __attribute__((ext_vector_type(2)));
typedef unsigned long long u64;
typedef unsigned int u32;

// ---------- math helpers ----------
__device__ __forceinline__ float fexp(float x) {
    return __builtin_amdgcn_exp2f(x * 1.4426950408889634f);
}
__device__ __forceinline__ float sigf(float x) {
    return __builtin_amdgcn_rcpf(1.0f + fexp(-x));
}
__device__ __forceinline__ float tanhf_fast(float x) {
    return 1.0f - 2.0f * __builtin_amdgcn_rcpf(1.0f + fexp(2.0f * x));
}
__device__ __forceinline__ unsigned short f16bits(f16 x) {
    union { f16 h; unsigned short u; } v; v.h = x; return v.u;
}
__device__ __forceinline__ u32 packh2(float a, float b) {
    half2t hv; hv.x = (_Float16)a; hv.y = (_Float16)b;
    return __builtin_bit_cast(u32, hv);
}

#if __has_builtin(__builtin_amdgcn_fdot2)
__device__ __forceinline__ float dot2u(u32 a, u32 b, float c) {
    return __builtin_amdgcn_fdot2(__builtin_bit_cast(half2t, a),
                                  __builtin_bit_cast(half2t, b), c, false);
}
#else
__device__ __forceinline__ float dot2u(u32 a, u32 b, float c) {
    half2t x = __builtin_bit_cast(half2t, a), y = __builtin_bit_cast(half2t, b);
    return fmaf((float)x.y, (float)y.y, fmaf((float)x.x, (float)y.x, c));
}
#endif

// system-scope (sc0 sc1) plain ops: bypass L1/L2, serviced at the IC --
// coherent across XCDs without RMWs or fences. (R0-proven transport.)
__device__ __forceinline__ u64 sysload(const u64* p) {
    return __hip_atomic_load(p, __ATOMIC_RELAXED, __HIP_MEMORY_SCOPE_SYSTEM);
}
__device__ __forceinline__ void sysstore(u64* p, u64 v) {
    __hip_atomic_store(p, v, __ATOMIC_RELAXED, __HIP_MEMORY_SCOPE_SYSTEM);
}

// ---------- embedding gather ----------
__global__ void gather_k(const int* __restrict__ words, const int* __restrict__ tags,
                         const float* __restrict__ wemb, const float* __restrict__ temb,
                         float* __restrict__ x0) {
    int t = blockIdx.x;
    int w = words[t], g = tags[t];
    for (int c = threadIdx.x; c < H; c += 128) {
        float v = (c < WD) ? wemb[w * WD + c] : temb[g * TD + (c - WD)];
        x0[t * H + c] = v;
    }
}

// ---------- generic GEMM: out[t][r] = sum_k X[t*ldx+k]*W[r*ldw+wofs+k] + bias1[r]+bias2[r]
__global__ __launch_bounds__(256) void gemm_tn(
    const float* __restrict__ X, int ldx,
    const float* __restrict__ Wt, int ldw, int wofs,
    const float* __restrict__ bias1, const float* __restrict__ bias2,
    float* __restrict__ out, int ldo, int Rt, int K) {
    __shared__ float Xs[64][17];
    __shared__ float Ws[64][17];
    const int tid = threadIdx.x;
    const int t0 = blockIdx.x * 64, r0 = blockIdx.y * 64;
    const int lr = tid >> 2, kq = (tid & 3) * 4;
    const int ti = tid >> 4, rj = tid & 15;
    float acc[4][4] = {};
    for (int k0 = 0; k0 < K; k0 += 16) {
        float4 xv = *(const float4*)(X + (size_t)(t0 + lr) * ldx + k0 + kq);
        Xs[lr][kq + 0] = xv.x; Xs[lr][kq + 1] = xv.y;
        Xs[lr][kq + 2] = xv.z; Xs[lr][kq + 3] = xv.w;
        int r = r0 + lr;
        float4 wv = make_float4(0.f, 0.f, 0.f, 0.f);
        if (r < Rt) wv = *(const float4*)(Wt + (size_t)r * ldw + wofs + k0 + kq);
        Ws[lr][kq + 0] = wv.x; Ws[lr][kq + 1] = wv.y;
        Ws[lr][kq + 2] = wv.z; Ws[lr][kq + 3] = wv.w;
        __syncthreads();
#pragma unroll
        for (int k = 0; k < 16; k++) {
            float xr[4], wr[4];
#pragma unroll
            for (int m = 0; m < 4; m++) xr[m] = Xs[ti * 4 + m][k];
#pragma unroll
            for (int n = 0; n < 4; n++) wr[n] = Ws[rj * 4 + n][k];
#pragma unroll
            for (int m = 0; m < 4; m++)
#pragma unroll
                for (int n = 0; n < 4; n++)
                    acc[m][n] = fmaf(xr[m], wr[n], acc[m][n]);
        }
        __syncthreads();
    }
    int rq = r0 + rj * 4;
    if (rq < Rt) {
        float b[4];
#pragma unroll
        for (int n = 0; n < 4; n++) {
            int r = rq + n;
            b[n] = (bias1 ? bias1[r] : 0.f) + (bias2 ? bias2[r] : 0.f);
        }
#pragma unroll
        for (int m = 0; m < 4; m++) {
            int t = t0 + ti * 4 + m;
            float4 o;
            o.x = acc[m][0] + b[0]; o.y = acc[m][1] + b[1];
            o.z = acc[m][2] + b[2]; o.w = acc[m][3] + b[3];
            *(float4*)(out + (size_t)t * ldo + rq) = o;
        }
    }
}

// ---------- init: tagged words, contiguous [dir][parity][NPAIR] ----------
__global__ void lstm_init5(const float* __restrict__ h0, u64* sA, u64* sB) {
    int tid = threadIdx.x;
    const int TOT = 2 * 2 * NPAIR;
    for (int i = tid; i < TOT; i += 256) { sA[i] = 0xFFFFULL; sB[i] = 0xFFFFULL; }
    __syncthreads();
    for (int p = tid; p < 2 * NPAIR; p += 256) {
        int d = p / NPAIR, pr = p - d * NPAIR;
        size_t off = (size_t)(d * 2 + 0) * NPAIR + pr;   // parity 0, tag 0
        f16 a0 = (f16)h0[d * H + 2 * pr], b0 = (f16)h0[d * H + 2 * pr + 1];
        sA[off] = 0ULL | ((u64)f16bits(a0) << 16) | ((u64)f16bits(b0) << 32);
        f16 a1 = (f16)h0[2 * H + d * H + 2 * pr], b1 = (f16)h0[2 * H + d * H + 2 * pr + 1];
        sB[off] = 0ULL | ((u64)f16bits(a1) << 16) | ((u64)f16bits(b1) << 32);
    }
}

// ---------- persistent LSTM layer v12: R0 structure, 2.5x fewer blocks ----------
// grid = 20 blocks (dir = b/10, blk = b%10), 1024 threads. Identical schedule
// and transport to the proven R0 kernel (two barriers/step, IC-scope tagged
// words, single-wave coalesced publish); only the decomposition changed:
// each block owns 40 h-rows (160 gate-rows), weights 129 KiB in LDS.
// Rationale: per-step cost is dominated by publish->detect across the
// all-to-all; polling streams drop 9600->3600 and producer jitter (max over
// 50 -> max over 20) shrinks, at the cost of ~+600cy LDS weight reads.
// Roles: tid<640 workers (4 k-slices per gate-row), tid in [640,820)
// pollers (one foreign word each), tid>=864 stagers (160 G values).
__global__ __launch_bounds__(1024, 1) void lstm_layer8(
    const float* __restrict__ G,     // [2][T][G4] gate inputs, biases folded
    const float* __restrict__ Whh,   // [2][G4][H]
    const float* __restrict__ c0l,   // [2][H] this layer
    float* __restrict__ xout,        // [T][2H]
    u64* __restrict__ slots) {       // [2][2][NPAIR]
    const int role = blockIdx.x;
    const int dir = role / NBLK_D, blk = role - dir * NBLK_D;
    const int tid = threadIdx.x;
    const float* Wd = Whh + (size_t)dir * G4 * H;
    const float* Gd = G + (size_t)dir * T * G4;
    u64* sd = slots + (size_t)dir * 2 * NPAIR;

    __shared__ u32 wlds[GR * WSTR];            // 160 rows x 202 u32 = 126.25 KiB
    __shared__ __align__(16) u32 hsh[NPAIR];   // h_s as 200 packed half2
    __shared__ float gsum[GR];                 // per-gate-row matvec sums
    __shared__ float gsh[2][GR];               // staged G, double-buffered

    // ---- one-time: pack weights fp32 -> half2 into LDS ----
    for (int idx = tid; idx < GR * 100; idx += 1024) {
        int row = idx / 100, c4 = idx - row * 100;
        int g = row / HB, r = row - g * HB;
        const float4* src = (const float4*)(Wd + (size_t)(g * H + blk * HB + r) * H);
        float4 f = src[c4];
        *(uint2*)&wlds[row * WSTR + c4 * 2] =
            make_uint2(packh2(f.x, f.y), packh2(f.z, f.w));
    }
    // pre-stage G(0); own h0 words into LDS
    if (tid >= 864) {
        int i = tid - 864, gg = i / HB, rr = i - gg * HB;
        int tt0 = dir ? (T - 1) : 0;
        gsh[0][i] = Gd[(size_t)tt0 * G4 + gg * H + blk * HB + rr];
    } else if (tid < OWNW) {
        u64 v = sysload(sd + blk * OWNW + tid);    // parity 0, tag 0
        hsh[blk * OWNW + tid] = (u32)(v >> 16);
    }
    float c = (tid < HB) ? c0l[dir * H + blk * HB + tid] : 0.f;
    __syncthreads();

#pragma clang loop unroll(disable)
    for (int s = 0; s < T; ++s) {
        if (tid >= 640 && tid < 640 + FORW) {
            // poller: one foreign word (parity s&1, tag s)
            int f = tid - 640;
            int widx = f + (f >= blk * OWNW ? OWNW : 0);
            u64* src = sd + (size_t)(s & 1) * NPAIR + widx;
            u64 v = sysload(src);
            int spins = 0;
            while ((unsigned)(v & 0xFFFFULL) != (unsigned)s) {
                if (++spins > 16384) {
                    v = __hip_atomic_fetch_add(src, 0ULL, __ATOMIC_RELAXED,
                                               __HIP_MEMORY_SCOPE_AGENT);
                } else {
                    v = sysload(src);
                }
            }
            hsh[widx] = (u32)(v >> 16);
        } else if (tid >= 864) {
            // stager: G(s+1) into the other parity half
            int sn = (s + 1 < T) ? (s + 1) : s;
            int tt = dir ? (T - 1 - sn) : sn;
            int i = tid - 864, gg = i / HB, rr = i - gg * HB;
            gsh[(s + 1) & 1][i] = Gd[(size_t)tt * G4 + gg * H + blk * HB + rr];
        }
        __syncthreads();   // (A) h_s complete in LDS

        if (tid < 640) {
            const int row = tid >> 2, sl = tid & 3;
            const u32* wp = &wlds[row * WSTR + sl * 50];
            const u32* hp = &hsh[sl * 50];
            float a0 = 0.f, a1 = 0.f, a2 = 0.f, a3 = 0.f;
#pragma unroll
            for (int i = 0; i < 12; ++i) {
                uint2 wv0 = *(const uint2*)&wp[4 * i];
                uint2 hv0 = *(const uint2*)&hp[4 * i];
                uint2 wv1 = *(const uint2*)&wp[4 * i + 2];
                uint2 hv1 = *(const uint2*)&hp[4 * i + 2];
                a0 = dot2u(wv0.x, hv0.x, a0);
                a1 = dot2u(wv0.y, hv0.y, a1);
                a2 = dot2u(wv1.x, hv1.x, a2);
                a3 = dot2u(wv1.y, hv1.y, a3);
            }
            {
                uint2 wv = *(const uint2*)&wp[48];
                uint2 hv = *(const uint2*)&hp[48];
                a0 = dot2u(wv.x, hv.x, a0);
                a1 = dot2u(wv.y, hv.y, a1);
            }
            float a = (a0 + a1) + (a2 + a3);
            a += __shfl_xor(a, 1);    // combine the 4 k-slices (adjacent lanes)
            a += __shfl_xor(a, 2);
            if (sl == 0) gsum[row] = a;
        }
        __syncthreads();   // (B) sums ready

        if (tid < 64) {    // wave 0: gate math + publish, intra-wave only
            const int r = tid;        // 40 active rows; lanes 40..63 idle math
            const int rr = (r < HB) ? r : 0;
            const float* gc = gsh[s & 1];
            float iv = gsum[rr]           + gc[rr];
            float fv = gsum[HB + rr]      + gc[HB + rr];
            float gv = gsum[2 * HB + rr]  + gc[2 * HB + rr];
            float ov = gsum[3 * HB + rr]  + gc[3 * HB + rr];
            float cn = sigf(fv) * c + sigf(iv) * tanhf_fast(gv);
            if (r < HB) c = cn;
            float hn = sigf(ov) * tanhf_fast(cn);
            u32 hb = (u32)f16bits((f16)hn);
            u32 lo = __shfl(hb, (2 * tid) & 63);
            u32 hi = __shfl(hb, (2 * tid + 1) & 63);
            if (tid < OWNW) {
                u32 pk = (lo & 0xFFFFu) | (hi << 16);
                hsh[blk * OWNW + tid] = pk;   // own slice of h_{s+1}, LDS fast-path
                sysstore(sd + (size_t)((s + 1) & 1) * NPAIR + blk * OWNW + tid,
                         (u64)(unsigned)(s + 1) | ((u64)pk << 16));
            }
            const int tt = dir ? (T - 1 - s) : s;
            if (r < HB)
                xout[(size_t)tt * (2 * H) + dir * H + blk * HB + r] = hn;
        }
    }
}

// ---------- fused pairwise scorer ----------
__global__ __launch_bounds__(256) void scores_k(
    const float* __restrict__ pi, const float* __restrict__ pj,
    const float* __restrict__ w2, const float* __restrict__ b2p,
    float* __restrict__ out) {
    __shared__ float Ps[16][401];
    __shared__ float Qs[16][401];
    __shared__ float w2s[400];
    const int tid = threadIdx.x;
    const int i0 = blockIdx.y * 16, j0 = blockIdx.x * 16;
    for (int r = 0; r < 16; r++) {
        for (int k = tid; k < MLP_H; k += 256) {
            Ps[r][k] = pi[(size_t)(i0 + r) * MLP_H + k];
            Qs[r][k] = pj[(size_t)(j0 + r) * MLP_H + k];
        }
    }
    for (int k = tid; k < MLP_H; k += 256) w2s[k] = w2[k];
    __syncthreads();
    const int ti = tid >> 4, tj = tid & 15;
    float acc = 0.f;
#pragma unroll 4
    for (int k = 0; k < MLP_H; k++) {
        float x = Ps[ti][k] + Qs[tj][k];
        acc = fmaf(w2s[k], tanhf_fast(x), acc);
    }
    const int i = i0 + ti, j = j0 + tj;
    out[(size_t)i * T + j] = (i == j) ? 0.f : (acc + b2p[0]);
}

extern "C" void kernel_launch(void* const* d_in, const int* in_sizes, int n_in,
                              void* d_out, int out_size, void* d_ws, size_t ws_size,
                              hipStream_t stream) {
    const int*   words = (const int*)d_in[0];
    const int*   tags  = (const int*)d_in[1];
    const float* wemb  = (const float*)d_in[2];
    const float* temb  = (const float*)d_in[3];
    const float* Wih0  = (const float*)d_in[4];
    const float* Whh0  = (const float*)d_in[5];
    const float* bih0  = (const float*)d_in[6];
    const float* bhh0  = (const float*)d_in[7];
    const float* Wih1  = (const float*)d_in[8];
    const float* Whh1  = (const float*)d_in[9];
    const float* bih1  = (const float*)d_in[10];
    const float* bhh1  = (const float*)d_in[11];
    const float* W1    = (const float*)d_in[12];
    const float* b1    = (const float*)d_in[13];
    const float* W2    = (const float*)d_in[14];
    const float* b2    = (const float*)d_in[15];
    const float* h0    = (const float*)d_in[16];
    const float* c0    = (const float*)d_in[17];
    float* out = (float*)d_out;

    float* W = (float*)d_ws;
    float* x0   = W;                 // 256*400 (dead after layer-0 GEMMs)
    float* x1   = W + 102400;        // 256*800
    float* hvec = W + 307200;        // 256*800
    float* Gb   = W + 512000;        // 2*256*1600 (reused for both layers)
    float* pi   = W + 1331200;       // 256*400
    float* pj   = W + 1433600;       // 256*400
    // word arrays overlap x0's region (x0 dead before lstm_init5 runs)
    u64* slotsA = (u64*)W;                               // 800 u64
    u64* slotsB = (u64*)(W + 2048);                      // 800 u64

    // 1. embedding gather
    gather_k<<<T, 128, 0, stream>>>(words, tags, wemb, temb, x0);

    // 2. layer-0 gate inputs
    for (int d = 0; d < 2; d++) {
        gemm_tn<<<dim3(4, 25), 256, 0, stream>>>(
            x0, H, Wih0 + (size_t)d * G4 * H, H, 0,
            bih0 + d * G4, bhh0 + d * G4,
            Gb + (size_t)d * T * G4, G4, G4, H);
    }
    // 3. init tagged words (x0 now dead), then LSTM layer 0
    lstm_init5<<<1, 256, 0, stream>>>(h0, slotsA, slotsB);
    lstm_layer8<<<2 * NBLK_D, 1024, 0, stream>>>(Gb, Whh0, c0, x1, slotsA);

    // 4. layer-1 gate inputs (K=800)
    for (int d = 0; d < 2; d++) {
        gemm_tn<<<dim3(4, 25), 256, 0, stream>>>(
            x1, 2 * H, Wih1 + (size_t)d * G4 * (2 * H), 2 * H, 0,
            bih1 + d * G4, bhh1 + d * G4,
            Gb + (size_t)d * T * G4, G4, G4, 2 * H);
    }
    // 5. LSTM layer 1
    lstm_layer8<<<2 * NBLK_D, 1024, 0, stream>>>(Gb, Whh1, c0 + 2 * H, hvec, slotsB);

    // 6. pi = hvec @ W1a.T + b1 ; pj = hvec @ W1b.T
    gemm_tn<<<dim3(4, 7), 256, 0, stream>>>(
        hvec, 2 * H, W1, G4, 0, b1, nullptr, pi, MLP_H, MLP_H, 2 * H);
    gemm_tn<<<dim3(4, 7), 256, 0, stream>>>(
        hvec, 2 * H, W1, G4, 2 * H, nullptr, nullptr, pj, MLP_H, MLP_H, 2 * H);

    // 7. fused pairwise scores
    scores_k<<<dim3(16, 16), 256, 0, stream>>>(pi, pj, W2, b2, out);
}

// Round 5
// 1536.488 us; speedup vs baseline: 1.4578x; 1.1671x over previous
//
#include <hip/hip_runtime.h>
#include <hip/hip_bf16.h>

#define T 256
#define H 400
#define G4 1600   // 4*H
#define WD 300
#define TD 100
#define MLP_H 400
#define NBLK 25         // blocks total; each handles BOTH directions
#define HB 16           // h-rows per block (per direction)
#define GR 64           // gate-rows per block per direction (4*HB)
#define WSTR 202        // LDS weight row stride in u32 (bank-conflict pad)
#define NPAIR 200       // 400 h values -> 200 tagged 64-bit words per dir

typedef _Float16 f16;
typedef _Float16 half2t __attribute__((ext_vector_type(2)));
typedef unsigned long long u64;
typedef unsigned int u32;

// ---------- math helpers ----------
__device__ __forceinline__ float fexp(float x) {
    return __builtin_amdgcn_exp2f(x * 1.4426950408889634f);
}
__device__ __forceinline__ float sigf(float x) {
    return __builtin_amdgcn_rcpf(1.0f + fexp(-x));
}
__device__ __forceinline__ float tanhf_fast(float x) {
    return 1.0f - 2.0f * __builtin_amdgcn_rcpf(1.0f + fexp(2.0f * x));
}
__device__ __forceinline__ unsigned short f16bits(f16 x) {
    union { f16 h; unsigned short u; } v; v.h = x; return v.u;
}
__device__ __forceinline__ u32 packh2(float a, float b) {
    half2t hv; hv.x = (_Float16)a; hv.y = (_Float16)b;
    return __builtin_bit_cast(u32, hv);
}

#if __has_builtin(__builtin_amdgcn_fdot2)
__device__ __forceinline__ float dot2u(u32 a, u32 b, float c) {
    return __builtin_amdgcn_fdot2(__builtin_bit_cast(half2t, a),
                                  __builtin_bit_cast(half2t, b), c, false);
}
#else
__device__ __forceinline__ float dot2u(u32 a, u32 b, float c) {
    half2t x = __builtin_bit_cast(half2t, a), y = __builtin_bit_cast(half2t, b);
    return fmaf((float)x.y, (float)y.y, fmaf((float)x.x, (float)y.x, c));
}
#endif

// system-scope (sc0 sc1) plain ops: bypass L1/L2, serviced at the IC --
// coherent across XCDs without RMWs or fences. (R0-proven transport.)
__device__ __forceinline__ u64 sysload(const u64* p) {
    return __hip_atomic_load(p, __ATOMIC_RELAXED, __HIP_MEMORY_SCOPE_SYSTEM);
}
__device__ __forceinline__ void sysstore(u64* p, u64 v) {
    __hip_atomic_store(p, v, __ATOMIC_RELAXED, __HIP_MEMORY_SCOPE_SYSTEM);
}

// ---------- embedding gather ----------
__global__ void gather_k(const int* __restrict__ words, const int* __restrict__ tags,
                         const float* __restrict__ wemb, const float* __restrict__ temb,
                         float* __restrict__ x0) {
    int t = blockIdx.x;
    int w = words[t], g = tags[t];
    for (int c = threadIdx.x; c < H; c += 128) {
        float v = (c < WD) ? wemb[w * WD + c] : temb[g * TD + (c - WD)];
        x0[t * H + c] = v;
    }
}

// ---------- generic GEMM: out[t][r] = sum_k X[t*ldx+k]*W[r*ldw+wofs+k] + bias1[r]+bias2[r]
__global__ __launch_bounds__(256) void gemm_tn(
    const float* __restrict__ X, int ldx,
    const float* __restrict__ Wt, int ldw, int wofs,
    const float* __restrict__ bias1, const float* __restrict__ bias2,
    float* __restrict__ out, int ldo, int Rt, int K) {
    __shared__ float Xs[64][17];
    __shared__ float Ws[64][17];
    const int tid = threadIdx.x;
    const int t0 = blockIdx.x * 64, r0 = blockIdx.y * 64;
    const int lr = tid >> 2, kq = (tid & 3) * 4;
    const int ti = tid >> 4, rj = tid & 15;
    float acc[4][4] = {};
    for (int k0 = 0; k0 < K; k0 += 16) {
        float4 xv = *(const float4*)(X + (size_t)(t0 + lr) * ldx + k0 + kq);
        Xs[lr][kq + 0] = xv.x; Xs[lr][kq + 1] = xv.y;
        Xs[lr][kq + 2] = xv.z; Xs[lr][kq + 3] = xv.w;
        int r = r0 + lr;
        float4 wv = make_float4(0.f, 0.f, 0.f, 0.f);
        if (r < Rt) wv = *(const float4*)(Wt + (size_t)r * ldw + wofs + k0 + kq);
        Ws[lr][kq + 0] = wv.x; Ws[lr][kq + 1] = wv.y;
        Ws[lr][kq + 2] = wv.z; Ws[lr][kq + 3] = wv.w;
        __syncthreads();
#pragma unroll
        for (int k = 0; k < 16; k++) {
            float xr[4], wr[4];
#pragma unroll
            for (int m = 0; m < 4; m++) xr[m] = Xs[ti * 4 + m][k];
#pragma unroll
            for (int n = 0; n < 4; n++) wr[n] = Ws[rj * 4 + n][k];
#pragma unroll
            for (int m = 0; m < 4; m++)
#pragma unroll
                for (int n = 0; n < 4; n++)
                    acc[m][n] = fmaf(xr[m], wr[n], acc[m][n]);
        }
        __syncthreads();
    }
    int rq = r0 + rj * 4;
    if (rq < Rt) {
        float b[4];
#pragma unroll
        for (int n = 0; n < 4; n++) {
            int r = rq + n;
            b[n] = (bias1 ? bias1[r] : 0.f) + (bias2 ? bias2[r] : 0.f);
        }
#pragma unroll
        for (int m = 0; m < 4; m++) {
            int t = t0 + ti * 4 + m;
            float4 o;
            o.x = acc[m][0] + b[0]; o.y = acc[m][1] + b[1];
            o.z = acc[m][2] + b[2]; o.w = acc[m][3] + b[3];
            *(float4*)(out + (size_t)t * ldo + rq) = o;
        }
    }
}

// ---------- init: tagged words, contiguous [dir][parity][NPAIR] ----------
__global__ void lstm_init5(const float* __restrict__ h0, u64* sA, u64* sB) {
    int tid = threadIdx.x;
    const int TOT = 2 * 2 * NPAIR;
    for (int i = tid; i < TOT; i += 256) { sA[i] = 0xFFFFULL; sB[i] = 0xFFFFULL; }
    __syncthreads();
    for (int p = tid; p < 2 * NPAIR; p += 256) {
        int d = p / NPAIR, pr = p - d * NPAIR;
        size_t off = (size_t)(d * 2 + 0) * NPAIR + pr;   // parity 0, tag 0
        f16 a0 = (f16)h0[d * H + 2 * pr], b0 = (f16)h0[d * H + 2 * pr + 1];
        sA[off] = 0ULL | ((u64)f16bits(a0) << 16) | ((u64)f16bits(b0) << 32);
        f16 a1 = (f16)h0[2 * H + d * H + 2 * pr], b1 = (f16)h0[2 * H + d * H + 2 * pr + 1];
        sB[off] = 0ULL | ((u64)f16bits(a1) << 16) | ((u64)f16bits(b1) << 32);
    }
}

// ---------- persistent LSTM layer v13: dual-direction interleave ----------
// grid = 25 blocks, 512 threads; each block owns h-rows [blk*16,+16) for
// BOTH directions (weights 101 KiB in LDS). Per step s, two phases:
//   phase F: workers matvec fwd(h_s) | pollers fetch BWD tag-s words |
//            stagers stage fwd G(s+1); barrier; wave0 fwd gates, publish
//            fwd tag s+1; barrier.
//   phase B: workers matvec bwd(h_s) | pollers fetch FWD tag-(s+1) words |
//            stagers stage bwd G(s+1); barrier; wave0 bwd gates, publish
//            bwd tag s+1; barrier.
// Each poll thus has a full compute phase between publish and need: the
// IC round trip (the dominant per-step term in R0/R3/R4) hides under the
// other direction's matvec. Per-direction transport/tag protocol is
// byte-identical to the R0-proven kernel (liveness & <=1-step-skew
// arguments unchanged); phases are block-uniform so no divergent barriers.
__global__ __launch_bounds__(512, 1) void lstm_layer_dual(
    const float* __restrict__ G,     // [2][T][G4] gate inputs, biases folded
    const float* __restrict__ Whh,   // [2][G4][H]
    const float* __restrict__ c0l,   // [2][H] this layer
    float* __restrict__ xout,        // [T][2H]
    u64* __restrict__ slots) {       // [2][2][NPAIR]
    const int blk = blockIdx.x;
    const int tid = threadIdx.x;
    u64* sdF = slots;
    u64* sdB = slots + 2 * NPAIR;

    __shared__ u32 wlds[2][GR * WSTR];           // 2 x 50.5 KiB = 101 KiB
    __shared__ __align__(16) u32 hshF[NPAIR];    // fwd h_s (200 packed half2)
    __shared__ __align__(16) u32 hshB[NPAIR];    // bwd h_s
    __shared__ float gsum[GR];                   // per-gate-row matvec sums
    __shared__ float gshF[2][GR];                // staged fwd G, double-buffered
    __shared__ float gshB[2][GR];                // staged bwd G

    // ---- one-time: pack weights fp32 -> half2 into LDS (both dirs) ----
    for (int idx = tid; idx < 2 * GR * 100; idx += 512) {
        int d = idx / (GR * 100), rem = idx - d * (GR * 100);
        int row = rem / 100, c4 = rem - row * 100;
        int g = row >> 4, r = row & 15;
        const float4* src = (const float4*)(
            Whh + (size_t)d * G4 * H + (size_t)(g * H + blk * HB + r) * H);
        float4 f = src[c4];
        *(uint2*)&wlds[d][row * WSTR + c4 * 2] =
            make_uint2(packh2(f.x, f.y), packh2(f.z, f.w));
    }
    // prologue: stage G(0) both dirs; own h0 words both dirs; poll fwd tag 0
    if (tid >= 448) {
        int i = tid - 448, gg = i >> 4, rr = i & 15;
        gshF[0][i] = G[(size_t)0 * G4 + gg * H + blk * HB + rr];             // fwd t=0
        gshB[0][i] = G[((size_t)T + (T - 1)) * G4 + gg * H + blk * HB + rr]; // bwd t=T-1
    } else if (tid < 8) {
        u64 v = sysload(sdF + blk * 8 + tid);            // parity 0, tag 0
        hshF[blk * 8 + tid] = (u32)(v >> 16);
    } else if (tid < 16) {
        u64 v = sysload(sdB + blk * 8 + (tid - 8));      // parity 0, tag 0
        hshB[blk * 8 + (tid - 8)] = (u32)(v >> 16);
    } else if (tid >= 256 && tid < 448) {
        int f = tid - 256;
        int widx = f + (f >= blk * 8 ? 8 : 0);
        u64* src = sdF + widx;                           // parity 0
        u64 v = sysload(src);
        int spins = 0;
        while ((unsigned)(v & 0xFFFFULL) != 0u) {
            if (++spins > 16384) {
                v = __hip_atomic_fetch_add(src, 0ULL, __ATOMIC_RELAXED,
                                           __HIP_MEMORY_SCOPE_AGENT);
            } else {
                v = sysload(src);
            }
        }
        hshF[widx] = (u32)(v >> 16);
    }
    float cf = (tid < 64) ? c0l[blk * HB + (tid & 15)] : 0.f;
    float cb = (tid < 64) ? c0l[H + blk * HB + (tid & 15)] : 0.f;
    __syncthreads();

#pragma clang loop unroll(disable)
    for (int s = 0; s < T; ++s) {
#pragma clang loop unroll(disable)
        for (int d = 0; d < 2; ++d) {
            // ---- parallel section ----
            if (tid >= 256 && tid < 448) {
                // poller: other-dir words needed next phase
                int f = tid - 256;
                int widx = f + (f >= blk * 8 ? 8 : 0);
                int tg = (d == 0) ? s : (s + 1);
                if (tg < T) {
                    u64* src = (d == 0 ? sdB : sdF) + (size_t)(tg & 1) * NPAIR + widx;
                    u64 v = sysload(src);
                    int spins = 0;
                    while ((unsigned)(v & 0xFFFFULL) != (unsigned)tg) {
                        if (++spins > 16384) {
                            v = __hip_atomic_fetch_add(src, 0ULL, __ATOMIC_RELAXED,
                                                       __HIP_MEMORY_SCOPE_AGENT);
                        } else {
                            v = sysload(src);
                        }
                    }
                    (d == 0 ? hshB : hshF)[widx] = (u32)(v >> 16);
                }
            } else if (tid >= 448) {
                // stager: this-dir G(s+1)
                int sn = (s + 1 < T) ? (s + 1) : s;
                int tt = d ? (T - 1 - sn) : sn;
                int i = tid - 448, gg = i >> 4, rr = i & 15;
                (d ? gshB : gshF)[(s + 1) & 1][i] =
                    G[((size_t)d * T + tt) * G4 + gg * H + blk * HB + rr];
            } else {
                // worker: matvec for this dir, gate row = tid>>2, slice = tid&3
                const int row = tid >> 2, sl = tid & 3;
                const u32* wp = &wlds[d][row * WSTR + sl * 50];
                const u32* hp = &(d ? hshB : hshF)[sl * 50];
                float a0 = 0.f, a1 = 0.f, a2 = 0.f, a3 = 0.f;
#pragma unroll
                for (int i = 0; i < 12; ++i) {
                    uint2 wv0 = *(const uint2*)&wp[4 * i];
                    uint2 hv0 = *(const uint2*)&hp[4 * i];
                    uint2 wv1 = *(const uint2*)&wp[4 * i + 2];
                    uint2 hv1 = *(const uint2*)&hp[4 * i + 2];
                    a0 = dot2u(wv0.x, hv0.x, a0);
                    a1 = dot2u(wv0.y, hv0.y, a1);
                    a2 = dot2u(wv1.x, hv1.x, a2);
                    a3 = dot2u(wv1.y, hv1.y, a3);
                }
                {
                    uint2 wv = *(const uint2*)&wp[48];
                    uint2 hv = *(const uint2*)&hp[48];
                    a0 = dot2u(wv.x, hv.x, a0);
                    a1 = dot2u(wv.y, hv.y, a1);
                }
                float a = (a0 + a1) + (a2 + a3);
                a += __shfl_xor(a, 1);    // combine the 4 k-slices
                a += __shfl_xor(a, 2);
                if (sl == 0) gsum[row] = a;
            }
            __syncthreads();   // (A) gsum ready; polled words landed

            if (tid < 64) {    // wave 0: gate math + publish for this dir
                const int r = tid & 15;
                const float* gc = (d ? gshB : gshF)[s & 1];
                float iv = gsum[r]      + gc[r];
                float fv = gsum[16 + r] + gc[16 + r];
                float gv = gsum[32 + r] + gc[32 + r];
                float ov = gsum[48 + r] + gc[48 + r];
                float c = d ? cb : cf;
                float cn = sigf(fv) * c + sigf(iv) * tanhf_fast(gv);
                if (d) cb = cn; else cf = cn;
                float hn = sigf(ov) * tanhf_fast(cn);
                u32 hb = (u32)f16bits((f16)hn);
                u32 lo = __shfl(hb, (2 * tid) & 63);
                u32 hi = __shfl(hb, (2 * tid + 1) & 63);
                if (tid < 8) {
                    u32 pk = (lo & 0xFFFFu) | (hi << 16);
                    (d ? hshB : hshF)[blk * 8 + tid] = pk;   // own slice, LDS fast-path
                    sysstore((d ? sdB : sdF) + (size_t)((s + 1) & 1) * NPAIR + blk * 8 + tid,
                             (u64)(unsigned)(s + 1) | ((u64)pk << 16));
                }
                const int tt = d ? (T - 1 - s) : s;
                if (tid < 16)
                    xout[(size_t)tt * (2 * H) + d * H + blk * HB + tid] = hn;
            }
            __syncthreads();   // (B) phase complete
        }
    }
}

// ---------- fused pairwise scorer ----------
__global__ __launch_bounds__(256) void scores_k(
    const float* __restrict__ pi, const float* __restrict__ pj,
    const float* __restrict__ w2, const float* __restrict__ b2p,
    float* __restrict__ out) {
    __shared__ float Ps[16][401];
    __shared__ float Qs[16][401];
    __shared__ float w2s[400];
    const int tid = threadIdx.x;
    const int i0 = blockIdx.y * 16, j0 = blockIdx.x * 16;
    for (int r = 0; r < 16; r++) {
        for (int k = tid; k < MLP_H; k += 256) {
            Ps[r][k] = pi[(size_t)(i0 + r) * MLP_H + k];
            Qs[r][k] = pj[(size_t)(j0 + r) * MLP_H + k];
        }
    }
    for (int k = tid; k < MLP_H; k += 256) w2s[k] = w2[k];
    __syncthreads();
    const int ti = tid >> 4, tj = tid & 15;
    float acc = 0.f;
#pragma unroll 4
    for (int k = 0; k < MLP_H; k++) {
        float x = Ps[ti][k] + Qs[tj][k];
        acc = fmaf(w2s[k], tanhf_fast(x), acc);
    }
    const int i = i0 + ti, j = j0 + tj;
    out[(size_t)i * T + j] = (i == j) ? 0.f : (acc + b2p[0]);
}

extern "C" void kernel_launch(void* const* d_in, const int* in_sizes, int n_in,
                              void* d_out, int out_size, void* d_ws, size_t ws_size,
                              hipStream_t stream) {
    const int*   words = (const int*)d_in[0];
    const int*   tags  = (const int*)d_in[1];
    const float* wemb  = (const float*)d_in[2];
    const float* temb  = (const float*)d_in[3];
    const float* Wih0  = (const float*)d_in[4];
    const float* Whh0  = (const float*)d_in[5];
    const float* bih0  = (const float*)d_in[6];
    const float* bhh0  = (const float*)d_in[7];
    const float* Wih1  = (const float*)d_in[8];
    const float* Whh1  = (const float*)d_in[9];
    const float* bih1  = (const float*)d_in[10];
    const float* bhh1  = (const float*)d_in[11];
    const float* W1    = (const float*)d_in[12];
    const float* b1    = (const float*)d_in[13];
    const float* W2    = (const float*)d_in[14];
    const float* b2    = (const float*)d_in[15];
    const float* h0    = (const float*)d_in[16];
    const float* c0    = (const float*)d_in[17];
    float* out = (float*)d_out;

    float* W = (float*)d_ws;
    float* x0   = W;                 // 256*400 (dead after layer-0 GEMMs)
    float* x1   = W + 102400;        // 256*800
    float* hvec = W + 307200;        // 256*800
    float* Gb   = W + 512000;        // 2*256*1600 (reused for both layers)
    float* pi   = W + 1331200;       // 256*400
    float* pj   = W + 1433600;       // 256*400
    // word arrays overlap x0's region (x0 dead before lstm_init5 runs)
    u64* slotsA = (u64*)W;                               // 800 u64
    u64* slotsB = (u64*)(W + 2048);                      // 800 u64

    // 1. embedding gather
    gather_k<<<T, 128, 0, stream>>>(words, tags, wemb, temb, x0);

    // 2. layer-0 gate inputs
    for (int d = 0; d < 2; d++) {
        gemm_tn<<<dim3(4, 25), 256, 0, stream>>>(
            x0, H, Wih0 + (size_t)d * G4 * H, H, 0,
            bih0 + d * G4, bhh0 + d * G4,
            Gb + (size_t)d * T * G4, G4, G4, H);
    }
    // 3. init tagged words (x0 now dead), then LSTM layer 0
    lstm_init5<<<1, 256, 0, stream>>>(h0, slotsA, slotsB);
    lstm_layer_dual<<<NBLK, 512, 0, stream>>>(Gb, Whh0, c0, x1, slotsA);

    // 4. layer-1 gate inputs (K=800)
    for (int d = 0; d < 2; d++) {
        gemm_tn<<<dim3(4, 25), 256, 0, stream>>>(
            x1, 2 * H, Wih1 + (size_t)d * G4 * (2 * H), 2 * H, 0,
            bih1 + d * G4, bhh1 + d * G4,
            Gb + (size_t)d * T * G4, G4, G4, 2 * H);
    }
    // 5. LSTM layer 1
    lstm_layer_dual<<<NBLK, 512, 0, stream>>>(Gb, Whh1, c0 + 2 * H, hvec, slotsB);

    // 6. pi = hvec @ W1a.T + b1 ; pj = hvec @ W1b.T
    gemm_tn<<<dim3(4, 7), 256, 0, stream>>>(
        hvec, 2 * H, W1, G4, 0, b1, nullptr, pi, MLP_H, MLP_H, 2 * H);
    gemm_tn<<<dim3(4, 7), 256, 0, stream>>>(
        hvec, 2 * H, W1, G4, 2 * H, nullptr, nullptr, pj, MLP_H, MLP_H, 2 * H);

    // 7. fused pairwise scores
    scores_k<<<dim3(16, 16), 256, 0, stream>>>(pi, pj, W2, b2, out);
}